// Round 8
// baseline (112.904 us; speedup 1.0000x reference)
//
#include <hip/hip_runtime.h>

#define DIM 8192
#define BATCH 256
#define BN 64
#define BK 64
#define KSPLIT 4
#define KLEN (DIM / KSPLIT)   // 2048 k per block
#define NSTEP (KLEN / BK)     // 32 steps
#define NT (DIM / BN)         // 128 n-tiles

typedef __attribute__((ext_vector_type(8))) short   short8;   // 8 bf16 frag
typedef __attribute__((ext_vector_type(4))) float   f32x4;
typedef __attribute__((ext_vector_type(4))) unsigned short u16x4;

__device__ __forceinline__ unsigned short f2b(float f) {
    unsigned u = __builtin_bit_cast(unsigned, f);
    u = (u + 0x7FFFu + ((u >> 16) & 1u)) >> 16;
    return (unsigned short)u;
}

#define WAITL0 asm volatile("s_waitcnt lgkmcnt(0)" ::: "memory")
#define CFENCE asm volatile("" ::: "memory")
#define SCHEDB __builtin_amdgcn_sched_barrier(0)

// ---- prepass: x f32 -> bf16 (ws+0, 4 MB) ----
__global__ __launch_bounds__(512) void cvt_x_kernel(const float* __restrict__ x,
                                                    unsigned short* __restrict__ xb) {
    int i = blockIdx.x * 512 + threadIdx.x;
    f32x4 v = reinterpret_cast<const f32x4*>(x)[i];
    u16x4 o;
    o[0] = f2b(v[0]); o[1] = f2b(v[1]); o[2] = f2b(v[2]); o[3] = f2b(v[3]);
    reinterpret_cast<u16x4*>(xb)[i] = o;
}

// LDS 16B-slot swizzle (bank-verified: 2 lanes/bank both sides = free)
__device__ __forceinline__ int F(int s) { return s ^ ((s >> 4) & 7); }

// ---- GEMM partials: p[ks][b][i] = sum_{j in ks-quarter} U[i,j]*x[b,j] ----
// grid 512 = 128 n-tiles x 4 k-quarters (2 blocks/CU), 512 threads (8 waves).
// FIFO-aware pipeline: per step T issue A(T+1) THEN U(T+4) (vmcnt FIFO: a wait
// on A never drains a young U); ds_write placed AFTER the MFMAs (lgkm FIFO:
// pre-MFMA wait covers only the B ds_reads). Raw s_barrier + lgkm-only drain.
__global__ __launch_bounds__(512, 4) void gemm_kernel(const unsigned short* __restrict__ xb,
                                                      const float* __restrict__ U,
                                                      float* __restrict__ part) {
    __shared__ unsigned short Blds[2][512 * 8];   // 2 bufs x 8KB, frag-linear

    const int tid  = threadIdx.x;
    const int lane = tid & 63;
    const int w    = tid >> 6;

    // XCD swizzle: bid&7 -> XCD; each XCD serves one (ks, nt-half): 1MB xb slab/L2
    const int bid = blockIdx.x;
    const int x8  = bid & 7, j8 = bid >> 3;
    const int ks  = x8 >> 1;
    const int nt  = (x8 & 1) * 64 + j8;

    const int n0    = nt * BN;
    const int kbase = ks * KLEN;

    // --- B stager: thread -> (U-row r of 64, k-oct k8): 8 consecutive floats
    const int r  = tid >> 3;
    const int k8 = (tid & 7) * 8;
    const float* Up = U + (long)(n0 + r) * DIM + kbase + k8;          // + t*BK
    const int wslot = F(((r >> 4) * 2 + (k8 >> 5)) * 64 + (r & 15) + 16 * ((k8 >> 3) & 3));

    // --- A frags: lane l -> batch row 32w + mf*16 + (l&15), k = h*32 + (l>>4)*8
    const unsigned short* Ap = xb + (long)(32 * w + (lane & 15)) * DIM + kbase + (lane >> 4) * 8;

    f32x4 acc[2][4];
#pragma unroll
    for (int mf = 0; mf < 2; ++mf)
#pragma unroll
        for (int nf = 0; nf < 4; ++nf)
            acc[mf][nf] = (f32x4){0.f, 0.f, 0.f, 0.f};

    f32x4  Upre[4][2];   // U(s) in slot s&3 (distance 4, HBM)
    short8 Aq[4];        // A(t) single set (distance 1, L2-hot)

    // ---- prologue: U(0)->buf0 directly; U(1..3)->Upre; A(0)->Aq
    {
        f32x4 u0 = *(const f32x4*)(Up);
        f32x4 u1 = *(const f32x4*)(Up + 4);
        Aq[0] = *(const short8*)(Ap);
        Aq[1] = *(const short8*)(Ap + 32);
        Aq[2] = *(const short8*)(Ap + 16 * DIM);
        Aq[3] = *(const short8*)(Ap + 16 * DIM + 32);
#pragma unroll
        for (int i = 1; i <= 3; ++i) {
            Upre[i][0] = *(const f32x4*)(Up + i * BK);
            Upre[i][1] = *(const f32x4*)(Up + i * BK + 4);
        }
        short8 pk;
#pragma unroll
        for (int j = 0; j < 4; ++j) { pk[j] = (short)f2b(u0[j]); pk[j + 4] = (short)f2b(u1[j]); }
        *(short8*)&Blds[0][wslot * 8] = pk;
    }
    WAITL0;
    CFENCE;
    __builtin_amdgcn_s_barrier();
    CFENCE;

    // step T (P=T&1): A(T+1)->Aq, U(T+4)->Upre[T&3] | ds_read B(T, buf P) |
    // MFMA | cvt Upre[(T+1)&3] -> ds_write buf P^1 | lgkm0 | s_barrier
#define STEPBODY(T, SI, SC, P)                                                       \
    do {                                                                             \
        { int ta = ((T) + 1 < NSTEP) ? (T) + 1 : NSTEP - 1;                          \
          Aq[0] = *(const short8*)(Ap + ta * BK);                                    \
          Aq[1] = *(const short8*)(Ap + ta * BK + 32);                               \
          Aq[2] = *(const short8*)(Ap + ta * BK + 16 * DIM);                         \
          Aq[3] = *(const short8*)(Ap + ta * BK + 16 * DIM + 32); }                  \
        { int tp = ((T) + 4 < NSTEP) ? (T) + 4 : NSTEP - 1;                          \
          Upre[SI][0] = *(const f32x4*)(Up + tp * BK);                               \
          Upre[SI][1] = *(const f32x4*)(Up + tp * BK + 4); }                         \
        SCHEDB;                                                                      \
        {                                                                            \
            short8 B0[4];                                                            \
            _Pragma("unroll")                                                        \
            for (int nf = 0; nf < 4; ++nf)                                           \
                B0[nf] = *(const short8*)&Blds[P][F((nf * 2 + 0) * 64 + lane) * 8];  \
            __builtin_amdgcn_s_setprio(1);                                           \
            _Pragma("unroll")                                                        \
            for (int mf = 0; mf < 2; ++mf)                                           \
                _Pragma("unroll")                                                    \
                for (int nf = 0; nf < 4; ++nf)                                       \
                    acc[mf][nf] = __builtin_amdgcn_mfma_f32_16x16x32_bf16(           \
                        AqP[mf * 2], B0[nf], acc[mf][nf], 0, 0, 0);                  \
            __builtin_amdgcn_s_setprio(0);                                           \
            short8 B1[4];                                                            \
            _Pragma("unroll")                                                        \
            for (int nf = 0; nf < 4; ++nf)                                           \
                B1[nf] = *(const short8*)&Blds[P][F((nf * 2 + 1) * 64 + lane) * 8];  \
            __builtin_amdgcn_s_setprio(1);                                           \
            _Pragma("unroll")                                                        \
            for (int mf = 0; mf < 2; ++mf)                                           \
                _Pragma("unroll")                                                    \
                for (int nf = 0; nf < 4; ++nf)                                       \
                    acc[mf][nf] = __builtin_amdgcn_mfma_f32_16x16x32_bf16(           \
                        AqP[mf * 2 + 1], B1[nf], acc[mf][nf], 0, 0, 0);              \
            __builtin_amdgcn_s_setprio(0);                                           \
        }                                                                            \
        {                                                                            \
            short8 pk;                                                               \
            _Pragma("unroll")                                                        \
            for (int j = 0; j < 4; ++j) {                                            \
                pk[j]     = (short)f2b(Upre[SC][0][j]);                              \
                pk[j + 4] = (short)f2b(Upre[SC][1][j]);                              \
            }                                                                        \
            *(short8*)&Blds[(P) ^ 1][wslot * 8] = pk;                                \
        }                                                                            \
        WAITL0;                                                                      \
        CFENCE;                                                                      \
        __builtin_amdgcn_s_barrier();                                                \
        CFENCE;                                                                      \
    } while (0)

    // A(T) must be consumed before A(T+1) load overwrites Aq: snapshot at step top.
    for (int tt = 0; tt < NSTEP; tt += 4) {
        { short8 AqP[4] = {Aq[0], Aq[1], Aq[2], Aq[3]}; STEPBODY(tt + 0, 0, 1, 0); }
        { short8 AqP[4] = {Aq[0], Aq[1], Aq[2], Aq[3]}; STEPBODY(tt + 1, 1, 2, 1); }
        { short8 AqP[4] = {Aq[0], Aq[1], Aq[2], Aq[3]}; STEPBODY(tt + 2, 2, 3, 0); }
        { short8 AqP[4] = {Aq[0], Aq[1], Aq[2], Aq[3]}; STEPBODY(tt + 3, 3, 0, 1); }
    }
#undef STEPBODY

    // ---- partial store: D row=(l>>4)*4+reg, col=l&15 (verified mapping)
    float* p = part + (long)ks * (BATCH * DIM);
    const int prow0 = 32 * w + (lane >> 4) * 4;
    const int pcol0 = n0 + (lane & 15);
#pragma unroll
    for (int mf = 0; mf < 2; ++mf)
#pragma unroll
        for (int nf = 0; nf < 4; ++nf) {
            float* o = p + (long)(prow0 + mf * 16) * DIM + pcol0 + nf * 16;
#pragma unroll
            for (int rr = 0; rr < 4; ++rr)
                o[(long)rr * DIM] = acc[mf][nf][rr];
        }
}

// ---- reduce: out = p0 + p1 + p2 + p3 ----
__global__ __launch_bounds__(512) void reduce_kernel(const float* __restrict__ part,
                                                     float* __restrict__ out) {
    long i = (long)blockIdx.x * 512 + threadIdx.x;   // f32x4 index, 524288 total
    const f32x4* p0 = reinterpret_cast<const f32x4*>(part);
    const f32x4* p1 = p0 + (long)BATCH * DIM / 4;
    const f32x4* p2 = p1 + (long)BATCH * DIM / 4;
    const f32x4* p3 = p2 + (long)BATCH * DIM / 4;
    f32x4 v = p0[i] + p1[i] + p2[i] + p3[i];
    reinterpret_cast<f32x4*>(out)[i] = v;
}

extern "C" void kernel_launch(void* const* d_in, const int* in_sizes, int n_in,
                              void* d_out, int out_size, void* d_ws, size_t ws_size,
                              hipStream_t stream) {
    const float* x = (const float*)d_in[0];     // [256, 8192] f32
    const float* U = (const float*)d_in[1];     // [8192, 8192] f32
    float* outp = (float*)d_out;                // [256, 8192] f32

    unsigned short* xb = (unsigned short*)d_ws;                    // 4 MB
    float* part = (float*)((char*)d_ws + (size_t)BATCH * DIM * 2); // 32 MB

    cvt_x_kernel<<<(BATCH * DIM / 4) / 512, 512, 0, stream>>>(x, xb);
    gemm_kernel<<<NT * KSPLIT, 512, 0, stream>>>(xb, U, part);
    reduce_kernel<<<(BATCH * DIM / 4) / 512, 512, 0, stream>>>(part, outp);
}